// Round 2
// baseline (1174.533 us; speedup 1.0000x reference)
//
#include <hip/hip_runtime.h>

#define S 25
#define Q 75
#define FEAT 64
#define HID 128
#define WAY 5
#define NITERS 10
#define LR 0.01f
#define THREADS 256
#define HPAD 132   // row stride for sH/sDh (16B aligned, bank-skewed)

// XOR-swizzled word index for W1: 16B granules within a 64-float row,
// quad' = quad ^ (row & 7)  (low 3 bits only; bijective per row).
__device__ __forceinline__ int w1word(int j, int k) {
    const int q = k >> 2;
    return j * FEAT + ((q & 8) << 2) + (((q ^ j) & 7) << 2) + (k & 3);
}

__global__ __launch_bounds__(THREADS, 2)
void episode_kernel(const float* __restrict__ qf,
                    const float* __restrict__ sf,
                    const int* __restrict__ st,
                    const float* __restrict__ W1g,
                    const float* __restrict__ b1g,
                    const float* __restrict__ W2g,
                    const float* __restrict__ b2g,
                    float* __restrict__ outg)
{
    __shared__ __align__(16) float sW1[HID * FEAT];
    __shared__ __align__(16) float sW2[WAY * HID];
    __shared__ __align__(16) float sX[S * FEAT];
    __shared__ __align__(16) float sH[S * HPAD];
    __shared__ __align__(16) float sDh[S * HPAD];
    __shared__ __align__(16) float sDl[S * 8];
    __shared__ float sb1[HID];
    __shared__ float sb2[8];
    __shared__ int sTgt[S];

    const int e = blockIdx.x;
    const int t = threadIdx.x;

    const float* eQ  = qf  + (size_t)e * Q * FEAT;
    const float* eS  = sf  + (size_t)e * S * FEAT;
    const int*   eT  = st  + (size_t)e * S;
    const float* eW1 = W1g + (size_t)e * HID * FEAT;
    const float* eb1 = b1g + (size_t)e * HID;
    const float* eW2 = W2g + (size_t)e * WAY * HID;
    const float* eb2 = b2g + (size_t)e * WAY;
    float*       eO  = outg + (size_t)e * Q * WAY;

    // ---- stage episode state into LDS ----
    for (int f = t; f < HID * FEAT; f += THREADS)
        sW1[w1word(f >> 6, f & 63)] = eW1[f];
    for (int f = t; f < S * FEAT; f += THREADS) sX[f] = eS[f];
    for (int f = t; f < WAY * HID; f += THREADS) sW2[f] = eW2[f];
    if (t < HID) sb1[t] = eb1[t];
    if (t < WAY) sb2[t] = eb2[t];
    if (t < S)   sTgt[t] = eT[t];
    __syncthreads();

    // forward mapping: lane-varying j (128 cols), 2 row-groups of 13 (row 12 duplicated, benign)
    const int j   = t & (HID - 1);
    const int grp = t >> 7;
    const int i0  = grp * 12;
    // gW1 mapping: lane-varying jl (64), wave-uniform k block of 16
    const int jl = t & 63;
    const int k0 = (t >> 6) << 4;

    for (int iter = 0; iter < NITERS; ++iter) {
        // ---------- forward hidden on support: h = relu(x W1^T + b1) ----------
        {
            float acc[13];
            const float bv = sb1[j];
            #pragma unroll
            for (int r = 0; r < 13; ++r) acc[r] = bv;
            for (int qd = 0; qd < 16; ++qd) {
                const float4 w = *(const float4*)&sW1[j * FEAT + ((qd & 8) << 2) + (((qd ^ j) & 7) << 2)];
                const float* xp = &sX[i0 * FEAT + (qd << 2)];
                #pragma unroll
                for (int r = 0; r < 13; ++r) {
                    const float4 s = *(const float4*)&xp[r * FEAT];
                    acc[r] = fmaf(w.x, s.x, acc[r]);
                    acc[r] = fmaf(w.y, s.y, acc[r]);
                    acc[r] = fmaf(w.z, s.z, acc[r]);
                    acc[r] = fmaf(w.w, s.w, acc[r]);
                }
            }
            #pragma unroll
            for (int r = 0; r < 13; ++r) sH[(i0 + r) * HPAD + j] = fmaxf(acc[r], 0.f);
        }
        __syncthreads();

        // ---------- logits = h W2^T + b2  (125 threads) ----------
        if (t < S * WAY) {
            const int i = t / WAY;
            const int w = t - i * WAY;
            const float* hr = &sH[i * HPAD];
            const float* wr = &sW2[w * HID];
            float a = sb2[w];
            for (int qd = 0; qd < 32; ++qd) {
                const float4 hv = *(const float4*)&hr[qd << 2];
                const float4 wv = *(const float4*)&wr[qd << 2];
                a += hv.x * wv.x + hv.y * wv.y + hv.z * wv.z + hv.w * wv.w;
            }
            sDl[i * 8 + w] = a;
        }
        __syncthreads();

        // ---------- softmax -> dlogits = (p - onehot)/S  (25 threads) ----------
        if (t < S) {
            const float l0 = sDl[t*8+0], l1 = sDl[t*8+1], l2 = sDl[t*8+2],
                        l3 = sDl[t*8+3], l4 = sDl[t*8+4];
            const float m = fmaxf(fmaxf(fmaxf(l0, l1), fmaxf(l2, l3)), l4);
            const float e0 = __expf(l0 - m), e1 = __expf(l1 - m), e2 = __expf(l2 - m),
                        e3 = __expf(l3 - m), e4 = __expf(l4 - m);
            const float inv = 1.f / (e0 + e1 + e2 + e3 + e4);
            const int tg = sTgt[t];
            const float sc = 1.f / (float)S;
            sDl[t*8+0] = (e0 * inv - (tg == 0 ? 1.f : 0.f)) * sc;
            sDl[t*8+1] = (e1 * inv - (tg == 1 ? 1.f : 0.f)) * sc;
            sDl[t*8+2] = (e2 * inv - (tg == 2 ? 1.f : 0.f)) * sc;
            sDl[t*8+3] = (e3 * inv - (tg == 3 ? 1.f : 0.f)) * sc;
            sDl[t*8+4] = (e4 * inv - (tg == 4 ? 1.f : 0.f)) * sc;
        }
        __syncthreads();

        // ---------- dh = (dl @ W2) * relu'(h); gW2/gb2 into regs ----------
        {
            const float w2v0 = sW2[0*HID + j], w2v1 = sW2[1*HID + j], w2v2 = sW2[2*HID + j],
                        w2v3 = sW2[3*HID + j], w2v4 = sW2[4*HID + j];
            #pragma unroll
            for (int r = 0; r < 13; ++r) {
                const int i = i0 + r;
                const float hv = sH[i * HPAD + j];
                const float4 d4 = *(const float4*)&sDl[i * 8];
                const float d5 = sDl[i * 8 + 4];
                const float d = d4.x * w2v0 + d4.y * w2v1 + d4.z * w2v2 + d4.w * w2v3 + d5 * w2v4;
                sDh[i * HPAD + j] = (hv > 0.f) ? d : 0.f;
            }
        }
        float gw20 = 0.f, gw21 = 0.f, gw22 = 0.f, gw23 = 0.f, gw24 = 0.f, gb2v = 0.f;
        if (t < HID) {
            for (int i = 0; i < S; ++i) {
                const float hv = sH[i * HPAD + t];
                const float4 d4 = *(const float4*)&sDl[i * 8];
                const float d5 = sDl[i * 8 + 4];
                gw20 = fmaf(d4.x, hv, gw20);
                gw21 = fmaf(d4.y, hv, gw21);
                gw22 = fmaf(d4.z, hv, gw22);
                gw23 = fmaf(d4.w, hv, gw23);
                gw24 = fmaf(d5, hv, gw24);
            }
        }
        if (t < WAY) {
            for (int i = 0; i < S; ++i) gb2v += sDl[i * 8 + t];
        }
        __syncthreads();   // all reads of pre-update W2 / sH done; sDh visible

        // ---------- apply W2/b2 update (safe: nothing reads sW2 until next iter) ----------
        if (t < HID) {
            sW2[0*HID + t] -= LR * gw20;
            sW2[1*HID + t] -= LR * gw21;
            sW2[2*HID + t] -= LR * gw22;
            sW2[3*HID + t] -= LR * gw23;
            sW2[4*HID + t] -= LR * gw24;
        }
        if (t < WAY) sb2[t] -= LR * gb2v;

        // ---------- gW1 = dh^T x ; update W1, b1 ----------
        {
            float a0[16], a1[16];
            #pragma unroll
            for (int c = 0; c < 16; ++c) { a0[c] = 0.f; a1[c] = 0.f; }
            for (int i = 0; i < S; ++i) {
                const float d0 = sDh[i * HPAD + jl];
                const float d1 = sDh[i * HPAD + 64 + jl];
                const float* xp = &sX[i * FEAT + k0];
                float xv[16];
                *(float4*)&xv[0]  = *(const float4*)&xp[0];
                *(float4*)&xv[4]  = *(const float4*)&xp[4];
                *(float4*)&xv[8]  = *(const float4*)&xp[8];
                *(float4*)&xv[12] = *(const float4*)&xp[12];
                #pragma unroll
                for (int c = 0; c < 16; ++c) {
                    a0[c] = fmaf(d0, xv[c], a0[c]);
                    a1[c] = fmaf(d1, xv[c], a1[c]);
                }
            }
            #pragma unroll
            for (int c = 0; c < 16; ++c) {
                sW1[w1word(jl,      k0 + c)] -= LR * a0[c];
                sW1[w1word(jl + 64, k0 + c)] -= LR * a1[c];
            }
        }
        if (t < HID) {
            float g = 0.f;
            for (int i = 0; i < S; ++i) g += sDh[i * HPAD + t];
            sb1[t] -= LR * g;
        }
        __syncthreads();
    }

    // ---------- query forward in 3 chunks of 25 rows (reuse sX/sH) ----------
    for (int qc = 0; qc < 3; ++qc) {
        for (int f = t; f < S * FEAT; f += THREADS) sX[f] = eQ[qc * S * FEAT + f];
        __syncthreads();
        {
            float acc[13];
            const float bv = sb1[j];
            #pragma unroll
            for (int r = 0; r < 13; ++r) acc[r] = bv;
            for (int qd = 0; qd < 16; ++qd) {
                const float4 w = *(const float4*)&sW1[j * FEAT + ((qd & 8) << 2) + (((qd ^ j) & 7) << 2)];
                const float* xp = &sX[i0 * FEAT + (qd << 2)];
                #pragma unroll
                for (int r = 0; r < 13; ++r) {
                    const float4 s = *(const float4*)&xp[r * FEAT];
                    acc[r] = fmaf(w.x, s.x, acc[r]);
                    acc[r] = fmaf(w.y, s.y, acc[r]);
                    acc[r] = fmaf(w.z, s.z, acc[r]);
                    acc[r] = fmaf(w.w, s.w, acc[r]);
                }
            }
            #pragma unroll
            for (int r = 0; r < 13; ++r) sH[(i0 + r) * HPAD + j] = fmaxf(acc[r], 0.f);
        }
        __syncthreads();
        if (t < S * WAY) {
            const int i = t / WAY;
            const int w = t - i * WAY;
            const float* hr = &sH[i * HPAD];
            const float* wr = &sW2[w * HID];
            float a = sb2[w];
            for (int qd = 0; qd < 32; ++qd) {
                const float4 hv = *(const float4*)&hr[qd << 2];
                const float4 wv = *(const float4*)&wr[qd << 2];
                a += hv.x * wv.x + hv.y * wv.y + hv.z * wv.z + hv.w * wv.w;
            }
            eO[(qc * S + i) * WAY + w] = a;
        }
        __syncthreads();
    }
}

extern "C" void kernel_launch(void* const* d_in, const int* in_sizes, int n_in,
                              void* d_out, int out_size, void* d_ws, size_t ws_size,
                              hipStream_t stream) {
    const float* qf  = (const float*)d_in[0];
    const float* sf  = (const float*)d_in[1];
    const int*   st  = (const int*)d_in[2];
    const float* W1  = (const float*)d_in[3];
    const float* b1  = (const float*)d_in[4];
    const float* W2  = (const float*)d_in[5];
    const float* b2  = (const float*)d_in[6];
    float* out = (float*)d_out;
    const int n_eps = in_sizes[0] / (Q * FEAT);   // 4000
    hipLaunchKernelGGL(episode_kernel, dim3(n_eps), dim3(THREADS), 0, stream,
                       qf, sf, st, W1, b1, W2, b2, out);
}

// Round 4
// 1133.461 us; speedup vs baseline: 1.0362x; 1.0362x over previous
//
#include <hip/hip_runtime.h>

#define S 25
#define Q 75
#define FEAT 64
#define HID 128
#define WAY 5
#define NITERS 10
#define LR 0.01f
#define THREADS 512
#define HPAD 132   // row stride for sH/sDh (16B aligned, bank-skewed)

// Swizzled word index of 16B granule q (0..15) of W1 row j.
// granule' = low3 XOR'd with row: spreads lane-varying row reads across 8 bank groups.
__device__ __forceinline__ int w1q(int j, int q) {
    return j * FEAT + ((q & 8) << 2) + (((q ^ j) & 7) << 2);
}

__global__ __launch_bounds__(THREADS, 4)
void episode_kernel(const float* __restrict__ qf,
                    const float* __restrict__ sf,
                    const int* __restrict__ st,
                    const float* __restrict__ W1g,
                    const float* __restrict__ b1g,
                    const float* __restrict__ W2g,
                    const float* __restrict__ b2g,
                    float* __restrict__ outg)
{
    __shared__ __align__(16) float sW1[HID * FEAT];
    __shared__ __align__(16) float sW2[WAY * HID];
    __shared__ __align__(16) float sX[S * FEAT];
    __shared__ __align__(16) float sH[S * HPAD];
    __shared__ __align__(16) float sDh[S * HPAD];
    __shared__ __align__(16) float sDl[S * 8];
    __shared__ float sb1[HID];
    __shared__ float sb2[8];
    __shared__ int sTgt[S];

    const int e = blockIdx.x;
    const int t = threadIdx.x;

    const float* eQ  = qf  + (size_t)e * Q * FEAT;
    const float* eS  = sf  + (size_t)e * S * FEAT;
    const int*   eT  = st  + (size_t)e * S;
    const float* eW1 = W1g + (size_t)e * HID * FEAT;
    const float* eb1 = b1g + (size_t)e * HID;
    const float* eW2 = W2g + (size_t)e * WAY * HID;
    const float* eb2 = b2g + (size_t)e * WAY;
    float*       eO  = outg + (size_t)e * Q * WAY;

    // ---- stage episode state into LDS (float4 everywhere) ----
    for (int f = t; f < HID * 16; f += THREADS) {           // 2048 quads of W1
        const int j = f >> 4, q = f & 15;
        *(float4*)&sW1[w1q(j, q)] = *(const float4*)&eW1[f << 2];
    }
    for (int f = t; f < S * 16; f += THREADS)               // 400 quads of X
        *(float4*)&sX[f << 2] = *(const float4*)&eS[f << 2];
    for (int f = t; f < WAY * 32; f += THREADS)             // 160 quads of W2
        *(float4*)&sW2[f << 2] = *(const float4*)&eW2[f << 2];
    if (t < HID) sb1[t] = eb1[t];
    if (t < WAY) sb2[t] = eb2[t];
    if (t < S)   sTgt[t] = eT[t];
    __syncthreads();

    // forward mapping: J=2 columns (jl, jl+64), R=4 rows per wave-group
    const int jl  = t & 63;
    const int rg  = t >> 6;        // wave index 0..7
    const int i0f = rg * 4;        // rows i0f..i0f+3 (valid if < 25)
    // dh mapping
    const int jd  = t & 127;
    const int rg2 = t >> 7;        // 0..3
    const int di0 = rg2 * 7;       // rows di0..di0+6 (guarded)
    // gW1 mapping: 2 columns (jg, jg+64) x 8 k-columns
    const int jg = t & 63;
    const int kb = t >> 6;         // 0..7 (wave-uniform)
    const int k0 = kb << 3;

    auto fwd_hidden = [&]() {
        float acc0[4], acc1[4];
        const float bv0 = sb1[jl];
        const float bv1 = sb1[jl + 64];
        #pragma unroll
        for (int r = 0; r < 4; ++r) { acc0[r] = bv0; acc1[r] = bv1; }
        int irw[4];
        #pragma unroll
        for (int r = 0; r < 4; ++r) {
            const int i = i0f + r;
            irw[r] = (i < S ? i : S - 1) * FEAT;
        }
        #pragma unroll 4
        for (int qd = 0; qd < 16; ++qd) {
            const float4 w0 = *(const float4*)&sW1[w1q(jl, qd)];
            const float4 w1 = *(const float4*)&sW1[w1q(jl + 64, qd)];
            #pragma unroll
            for (int r = 0; r < 4; ++r) {
                const float4 xv = *(const float4*)&sX[irw[r] + (qd << 2)];
                acc0[r] = fmaf(w0.x, xv.x, acc0[r]);
                acc0[r] = fmaf(w0.y, xv.y, acc0[r]);
                acc0[r] = fmaf(w0.z, xv.z, acc0[r]);
                acc0[r] = fmaf(w0.w, xv.w, acc0[r]);
                acc1[r] = fmaf(w1.x, xv.x, acc1[r]);
                acc1[r] = fmaf(w1.y, xv.y, acc1[r]);
                acc1[r] = fmaf(w1.z, xv.z, acc1[r]);
                acc1[r] = fmaf(w1.w, xv.w, acc1[r]);
            }
        }
        #pragma unroll
        for (int r = 0; r < 4; ++r) {
            const int i = i0f + r;
            if (i < S) {
                sH[i * HPAD + jl]      = fmaxf(acc0[r], 0.f);
                sH[i * HPAD + jl + 64] = fmaxf(acc1[r], 0.f);
            }
        }
    };

    for (int iter = 0; iter < NITERS; ++iter) {
        // ---------- forward hidden on support ----------
        fwd_hidden();
        __syncthreads();

        // ---------- logits + softmax + dlogits in one phase (8-lane groups) ----------
        if (t < 200) {
            const int li = t >> 3, lw = t & 7;
            float a = -3.0e38f;
            if (lw < WAY) {
                const float* hr = &sH[li * HPAD];
                const float* wr = &sW2[lw * HID];
                a = sb2[lw];
                #pragma unroll 8
                for (int qd = 0; qd < 32; ++qd) {
                    const float4 hv = *(const float4*)&hr[qd << 2];
                    const float4 wv = *(const float4*)&wr[qd << 2];
                    a += hv.x * wv.x + hv.y * wv.y + hv.z * wv.z + hv.w * wv.w;
                }
            }
            float m = a;
            #pragma unroll
            for (int d = 1; d < 8; d <<= 1) m = fmaxf(m, __shfl_xor(m, d, 8));
            const float ev = (lw < WAY) ? __expf(a - m) : 0.f;
            float sum = ev;
            #pragma unroll
            for (int d = 1; d < 8; d <<= 1) sum += __shfl_xor(sum, d, 8);
            if (lw < WAY) {
                const float p = ev / sum;
                sDl[li * 8 + lw] = (p - (sTgt[li] == lw ? 1.f : 0.f)) * (1.f / (float)S);
            }
        }
        __syncthreads();

        // ---------- dh (all threads) ; gW2 (waves 6-7) ; gb2 (wave 5) ----------
        {
            const float w20 = sW2[0 * HID + jd], w21 = sW2[1 * HID + jd],
                        w22 = sW2[2 * HID + jd], w23 = sW2[3 * HID + jd],
                        w24 = sW2[4 * HID + jd];
            #pragma unroll
            for (int r = 0; r < 7; ++r) {
                const int i = di0 + r;
                if (i < S) {
                    const float hv = sH[i * HPAD + jd];
                    const float4 d4 = *(const float4*)&sDl[i * 8];
                    const float d5 = sDl[i * 8 + 4];
                    const float d = d4.x * w20 + d4.y * w21 + d4.z * w22 + d4.w * w23 + d5 * w24;
                    sDh[i * HPAD + jd] = (hv > 0.f) ? d : 0.f;
                }
            }
        }
        float gw2a0 = 0.f, gw2a1 = 0.f, gw2a2 = 0.f, gw2a3 = 0.f, gw2a4 = 0.f;
        if (t >= 384) {
            const int j2 = t - 384;
            for (int i = 0; i < S; ++i) {
                const float hv = sH[i * HPAD + j2];
                const float4 d4 = *(const float4*)&sDl[i * 8];
                const float d5 = sDl[i * 8 + 4];
                gw2a0 = fmaf(d4.x, hv, gw2a0);
                gw2a1 = fmaf(d4.y, hv, gw2a1);
                gw2a2 = fmaf(d4.z, hv, gw2a2);
                gw2a3 = fmaf(d4.w, hv, gw2a3);
                gw2a4 = fmaf(d5, hv, gw2a4);
            }
        }
        float gb2a = 0.f;
        if (t >= 320 && t < 320 + WAY) {
            for (int i = 0; i < S; ++i) gb2a += sDl[i * 8 + (t - 320)];
        }
        __syncthreads();

        // ---------- apply W2/b2 ; gW1 (float4 RMW, swizzle-clean) ; b1 ----------
        if (t >= 384) {
            const int j2 = t - 384;
            sW2[0 * HID + j2] -= LR * gw2a0;
            sW2[1 * HID + j2] -= LR * gw2a1;
            sW2[2 * HID + j2] -= LR * gw2a2;
            sW2[3 * HID + j2] -= LR * gw2a3;
            sW2[4 * HID + j2] -= LR * gw2a4;
        }
        if (t >= 320 && t < 320 + WAY) sb2[t - 320] -= LR * gb2a;
        {
            float a0[8], a1[8];
            #pragma unroll
            for (int c = 0; c < 8; ++c) { a0[c] = 0.f; a1[c] = 0.f; }
            #pragma unroll 5
            for (int i = 0; i < S; ++i) {
                const float d0 = sDh[i * HPAD + jg];
                const float d1 = sDh[i * HPAD + 64 + jg];
                const float4 x0 = *(const float4*)&sX[i * FEAT + k0];
                const float4 x1 = *(const float4*)&sX[i * FEAT + k0 + 4];
                a0[0] = fmaf(d0, x0.x, a0[0]); a0[1] = fmaf(d0, x0.y, a0[1]);
                a0[2] = fmaf(d0, x0.z, a0[2]); a0[3] = fmaf(d0, x0.w, a0[3]);
                a0[4] = fmaf(d0, x1.x, a0[4]); a0[5] = fmaf(d0, x1.y, a0[5]);
                a0[6] = fmaf(d0, x1.z, a0[6]); a0[7] = fmaf(d0, x1.w, a0[7]);
                a1[0] = fmaf(d1, x0.x, a1[0]); a1[1] = fmaf(d1, x0.y, a1[1]);
                a1[2] = fmaf(d1, x0.z, a1[2]); a1[3] = fmaf(d1, x0.w, a1[3]);
                a1[4] = fmaf(d1, x1.x, a1[4]); a1[5] = fmaf(d1, x1.y, a1[5]);
                a1[6] = fmaf(d1, x1.z, a1[6]); a1[7] = fmaf(d1, x1.w, a1[7]);
            }
            const int q0 = kb << 1, q1 = q0 + 1;
            {
                float4* p = (float4*)&sW1[w1q(jg, q0)];
                float4 v = *p;
                v.x -= LR * a0[0]; v.y -= LR * a0[1]; v.z -= LR * a0[2]; v.w -= LR * a0[3];
                *p = v;
            }
            {
                float4* p = (float4*)&sW1[w1q(jg, q1)];
                float4 v = *p;
                v.x -= LR * a0[4]; v.y -= LR * a0[5]; v.z -= LR * a0[6]; v.w -= LR * a0[7];
                *p = v;
            }
            {
                float4* p = (float4*)&sW1[w1q(jg + 64, q0)];
                float4 v = *p;
                v.x -= LR * a1[0]; v.y -= LR * a1[1]; v.z -= LR * a1[2]; v.w -= LR * a1[3];
                *p = v;
            }
            {
                float4* p = (float4*)&sW1[w1q(jg + 64, q1)];
                float4 v = *p;
                v.x -= LR * a1[4]; v.y -= LR * a1[5]; v.z -= LR * a1[6]; v.w -= LR * a1[7];
                *p = v;
            }
        }
        if (t < HID) {
            float g = 0.f;
            for (int i = 0; i < S; ++i) g += sDh[i * HPAD + t];
            sb1[t] -= LR * g;
        }
        __syncthreads();
    }

    // ---------- query forward in 3 chunks of 25 rows ----------
    for (int qc = 0; qc < 3; ++qc) {
        for (int f = t; f < S * 16; f += THREADS)
            *(float4*)&sX[f << 2] = *(const float4*)&eQ[qc * (S * FEAT) + (f << 2)];
        __syncthreads();
        fwd_hidden();
        __syncthreads();
        if (t < 200) {
            const int li = t >> 3, lw = t & 7;
            if (lw < WAY) {
                const float* hr = &sH[li * HPAD];
                const float* wr = &sW2[lw * HID];
                float a = sb2[lw];
                #pragma unroll 8
                for (int qd = 0; qd < 32; ++qd) {
                    const float4 hv = *(const float4*)&hr[qd << 2];
                    const float4 wv = *(const float4*)&wr[qd << 2];
                    a += hv.x * wv.x + hv.y * wv.y + hv.z * wv.z + hv.w * wv.w;
                }
                eO[(qc * S + li) * WAY + lw] = a;
            }
        }
        __syncthreads();
    }
}

extern "C" void kernel_launch(void* const* d_in, const int* in_sizes, int n_in,
                              void* d_out, int out_size, void* d_ws, size_t ws_size,
                              hipStream_t stream) {
    const float* qf  = (const float*)d_in[0];
    const float* sf  = (const float*)d_in[1];
    const int*   st  = (const int*)d_in[2];
    const float* W1  = (const float*)d_in[3];
    const float* b1  = (const float*)d_in[4];
    const float* W2  = (const float*)d_in[5];
    const float* b2  = (const float*)d_in[6];
    float* out = (float*)d_out;
    const int n_eps = in_sizes[0] / (Q * FEAT);   // 4000
    hipLaunchKernelGGL(episode_kernel, dim3(n_eps), dim3(THREADS), 0, stream,
                       qf, sf, st, W1, b1, W2, b2, out);
}